// Round 8
// baseline (39.464 us; speedup 1.0000x reference)
//
#include <hip/hip_runtime.h>
#include <math.h>

typedef float    f32x2 __attribute__((ext_vector_type(2)));
typedef float    f32x4 __attribute__((ext_vector_type(4)));
typedef _Float16 f16x2 __attribute__((ext_vector_type(2)));

static constexpr int B_ = 4;
static constexpr int L_ = 256;
static constexpr int K_ = 256;
static constexpr int H_ = 768;
static constexpr int H2_ = H_ / 2;       // 384 f16-pairs per row
static constexpr int VAL_SIZE_ = 10000;
static constexpr float INV_TEMPER = 0.03608439182435161f; // 1/sqrt(768)

// ---------------- f16 pair helpers ----------------
__device__ __forceinline__ unsigned pack_f16x2(float a, float b) {
  f16x2 p = {(_Float16)a, (_Float16)b};   // RNE converts
  return __builtin_bit_cast(unsigned, p);
}
__device__ __forceinline__ float fdot2u(unsigned a, unsigned b, float c) {
#if __has_builtin(__builtin_amdgcn_fdot2)
  return __builtin_amdgcn_fdot2(__builtin_bit_cast(f16x2, a),
                                __builtin_bit_cast(f16x2, b), c, false);
#else
  f16x2 va = __builtin_bit_cast(f16x2, a);
  f16x2 vb = __builtin_bit_cast(f16x2, b);
  return c + (float)va.x * (float)vb.x + (float)va.y * (float)vb.y;
#endif
}

// ---------------- non-temporal load (native vec type) ----------------
__device__ __forceinline__ float4 nt_load4(const float* p) {
  f32x4 v = __builtin_nontemporal_load(reinterpret_cast<const f32x4*>(p));
  return make_float4(v.x, v.y, v.z, v.w);
}

// ---------------- fp8 e4m3fn (OCP) helpers ----------------
#if __has_builtin(__builtin_amdgcn_cvt_pk_fp8_f32)
#define HW_FP8_ENC 1
#endif
#if __has_builtin(__builtin_amdgcn_cvt_pk_f32_fp8)
#define HW_FP8_DEC 1
#endif

__device__ __forceinline__ unsigned fp8_enc1(float f) {
  unsigned s = (__float_as_uint(f) >> 31) << 7;
  float af = fminf(fabsf(f), 448.0f);
  unsigned em;
  if (af < 0.015625f) {
    em = (unsigned)rintf(af * 512.0f);
  } else {
    unsigned m = __float_as_uint(af);
    m += 0x7ffffu + ((m >> 20) & 1u);
    em = (m >> 20) - (120u << 3);
  }
  return s | em;
}
__device__ __forceinline__ float fp8_dec1(unsigned b) {
  unsigned em = b & 0x7fu;
  unsigned sbit = (b & 0x80u) << 24;
  float n = __uint_as_float(sbit | ((em + 960u) << 20));
  float sub = __uint_as_float(sbit | 0x3F800000u) * (float)em * 0.001953125f;
  return em >= 8u ? n : sub;
}
__device__ __forceinline__ unsigned fp8_enc4(float a, float b, float c, float d) {
#ifdef HW_FP8_ENC
  int w = 0;
  w = __builtin_amdgcn_cvt_pk_fp8_f32(a, b, w, false);
  w = __builtin_amdgcn_cvt_pk_fp8_f32(c, d, w, true);
  return (unsigned)w;
#else
  return fp8_enc1(a) | (fp8_enc1(b) << 8) | (fp8_enc1(c) << 16) | (fp8_enc1(d) << 24);
#endif
}
__device__ __forceinline__ void fp8_dec4(unsigned w, float* o) {
#ifdef HW_FP8_DEC
  f32x2 lo = __builtin_amdgcn_cvt_pk_f32_fp8((int)w, false);
  f32x2 hi = __builtin_amdgcn_cvt_pk_f32_fp8((int)w, true);
  o[0] = lo.x; o[1] = lo.y; o[2] = hi.x; o[3] = hi.y;
#else
  o[0] = fp8_dec1(w & 0xffu);
  o[1] = fp8_dec1((w >> 8) & 0xffu);
  o[2] = fp8_dec1((w >> 16) & 0xffu);
  o[3] = fp8_dec1(w >> 24);
#endif
}

static constexpr int TBLK = (K_ / 64) * (H_ / 64) * B_;    // 192 transpose blocks
static constexpr int SBLK = (L_ / 4) * B_;                 // 256 fused blocks
static constexpr int CBLK = (VAL_SIZE_ * H_) / 4096;       // 1875 convert blocks

// ---------------------------------------------------------------------------
// Kernel 1 (prep): blocks [0,TBLK) gather+transpose keys -> f16-pair
// ET2[b][h2][k]; blocks [TBLK, TBLK+CBLK) convert val table f32 -> fp8 VT8.
// Both independent. block 256.
// ---------------------------------------------------------------------------
__global__ __launch_bounds__(256)
void k_prep(const int* __restrict__ key_seq,
            const float* __restrict__ key_emb,
            const float* __restrict__ vtab,
            unsigned* __restrict__ ET2,
            unsigned char* __restrict__ VT8) {
  __shared__ float tile[64][65];
  const int t = threadIdx.x;

  if (blockIdx.x >= TBLK) {
    // ---- val table f32 -> fp8; block covers 4096 contiguous floats ----
    const size_t base = (size_t)(blockIdx.x - TBLK) * 4096;
#pragma unroll
    for (int c = 0; c < 4; ++c) {
      const size_t e0 = base + (size_t)c * 1024 + (size_t)t * 4;
      const float4 a = nt_load4(vtab + e0);
      *reinterpret_cast<unsigned*>(VT8 + e0) = fp8_enc4(a.x, a.y, a.z, a.w);
    }
    return;
  }

  const int blk  = blockIdx.x;
  const int kb   = (blk % (K_ / 64)) * 64;
  const int hb   = ((blk / (K_ / 64)) % (H_ / 64)) * 64;
  const int b    = blk / ((K_ / 64) * (H_ / 64));
  const int sub  = t >> 6;
  const int lane = t & 63;

#pragma unroll
  for (int p = 0; p < 16; ++p) {
    const int kl  = p * 4 + sub;
    const int row = key_seq[b * K_ + kb + kl];              // wave-uniform
    tile[kl][lane] = key_emb[(size_t)row * H_ + hb + lane]; // coalesced
  }
  __syncthreads();
#pragma unroll
  for (int p = 0; p < 8; ++p) {
    const int hl2 = p * 4 + sub;                            // 0..31
    ET2[((size_t)b * H2_ + (hb >> 1) + hl2) * K_ + kb + lane] =
        pack_f16x2(tile[lane][2 * hl2], tile[lane][2 * hl2 + 1]);
  }
}

// ---------------------------------------------------------------------------
// Kernel 2 (fused): scores + masked softmax + compaction + PV + residual.
// 256 blocks x 512 threads. Waves 0-3: scores for 4 l-rows (as r7).
// Waves 4-7: stage vmat, then join for PV. PV: wave pair (r, r+4) gathers
// row r, one full 768B fp8 row per wave per j (uint3/lane). No global P.
// ---------------------------------------------------------------------------
__global__ __launch_bounds__(512)
void k_scores_pv(const float* __restrict__ hidden,
                 const unsigned* __restrict__ ET2,
                 const int* __restrict__ mask,
                 const int* __restrict__ vmat,
                 const unsigned char* __restrict__ VT8,
                 float* __restrict__ out) {
  __shared__ unsigned hid2[4 * H2_];   // 6 KB  (f16 pairs along h)
  __shared__ float4   part[4][256];    // 16 KB
  __shared__ int      vmat_lds[4][K_]; // 4 KB
  __shared__ float    pw[4][K_];       // 4 KB  compacted weights
  __shared__ int      vidx[4][K_];     // 4 KB  compacted indices
  __shared__ float    osum[4][H_];     // 12 KB row partials
  __shared__ int      nrow[4];

  const int t  = threadIdx.x;
  const int l0 = (blockIdx.x & 63) * 4;   // 64 l-groups per batch
  const int b  = blockIdx.x >> 6;

  // ---- stage: hidden rows as f16 pairs (all threads), vmat rows (waves 4-7)
  const float* hsrc = hidden + ((size_t)b * L_ + l0) * H_;
  for (int i = t; i < 4 * H2_; i += 512) {
    const float2 hv = *reinterpret_cast<const float2*>(hsrc + 2 * i);
    hid2[i] = pack_f16x2(hv.x, hv.y);
  }
  if (t >= 256) {
    const int i  = t - 256;
    const int r  = i >> 6;
    const int c4 = (i & 63) * 4;
    *reinterpret_cast<int4*>(&vmat_lds[r][c4]) =
        *reinterpret_cast<const int4*>(vmat + ((size_t)b * L_ + l0 + r) * K_ + c4);
  }
  __syncthreads();

  // ---- scores: waves 0-3 ----
  if (t < 256) {
    const int kq = t & 63;
    const int hq = t >> 6;
    float4 acc[4];
#pragma unroll
    for (int l = 0; l < 4; ++l) acc[l] = make_float4(0.f, 0.f, 0.f, 0.f);

    const unsigned* etp =
        ET2 + (size_t)b * H2_ * K_ + (size_t)(hq * 96) * K_ + kq * 4;
    const int hbase2 = hq * 96;
#pragma unroll 4
    for (int hh = 0; hh < 96; ++hh) {
      const uint4 e = *reinterpret_cast<const uint4*>(etp + (size_t)hh * K_);
#pragma unroll
      for (int l = 0; l < 4; ++l) {
        const unsigned hv2 = hid2[l * H2_ + hbase2 + hh];  // LDS broadcast
        acc[l].x = fdot2u(e.x, hv2, acc[l].x);
        acc[l].y = fdot2u(e.y, hv2, acc[l].y);
        acc[l].z = fdot2u(e.z, hv2, acc[l].z);
        acc[l].w = fdot2u(e.w, hv2, acc[l].w);
      }
    }
#pragma unroll
    for (int l = 0; l < 4; ++l) part[l][t] = acc[l];
  }
  __syncthreads();

  if (t < 256) {
    const int kq2 = t & 63;
    const int l2  = t >> 6;
    float4 a = part[l2][kq2];
    const float4 b1 = part[l2][64 + kq2];
    const float4 c  = part[l2][128 + kq2];
    const float4 d  = part[l2][192 + kq2];
    a.x += b1.x + c.x + d.x;
    a.y += b1.y + c.y + d.y;
    a.z += b1.z + c.z + d.z;
    a.w += b1.w + c.w + d.w;

    const int lrow = l0 + l2;
    const int4 m4 = *reinterpret_cast<const int4*>(
        mask + ((size_t)b * L_ + lrow) * K_ + kq2 * 4);
    float ex[4];
    ex[0] = (m4.x > 0) ? expf(a.x * INV_TEMPER) : 0.f;
    ex[1] = (m4.y > 0) ? expf(a.y * INV_TEMPER) : 0.f;
    ex[2] = (m4.z > 0) ? expf(a.z * INV_TEMPER) : 0.f;
    ex[3] = (m4.w > 0) ? expf(a.w * INV_TEMPER) : 0.f;

    float s = ex[0] + ex[1] + ex[2] + ex[3];
#pragma unroll
    for (int off = 32; off > 0; off >>= 1) s += __shfl_down(s, off);
    const float tot = __shfl(s, 0) + 1e-10f;
    const float rtot = 1.0f / tot;

    // ---- deterministic in-LDS compaction of nonzero p (per row = wave) ----
    const unsigned long long lt = (1ull << kq2) - 1ull;
    unsigned long long m[4];
    int run = 0;
    int pos[4];
#pragma unroll
    for (int cc = 0; cc < 4; ++cc) {
      m[cc] = __ballot(ex[cc] != 0.f);
      pos[cc] = run + (int)__popcll(m[cc] & lt);
      run += (int)__popcll(m[cc]);
    }
#pragma unroll
    for (int cc = 0; cc < 4; ++cc) {
      if (ex[cc] != 0.f) {
        pw[l2][pos[cc]]   = ex[cc] * rtot;
        vidx[l2][pos[cc]] = vmat_lds[l2][kq2 * 4 + cc];
      }
    }
    if (kq2 == 0) nrow[l2] = run;
  }
  __syncthreads();

  // ---- PV: all 8 waves; pair (r, r+4) covers row r ----
  const int w    = t >> 6;
  const int lane = t & 63;
  const int r    = w & 3;
  const int half = w >> 2;
  const int n    = nrow[r];

  float acc[12];
#pragma unroll
  for (int i = 0; i < 12; ++i) acc[i] = 0.f;

#pragma unroll 4
  for (int j = half; j < n; j += 2) {
    const float wgt = pw[r][j];                   // LDS broadcast
    const int   idx = vidx[r][j];
    const uint3 v = *reinterpret_cast<const uint3*>(
        VT8 + (size_t)idx * H_ + lane * 12);      // 12B x 64 lanes = 768B row
    float f[12];
    fp8_dec4(v.x, f);
    fp8_dec4(v.y, f + 4);
    fp8_dec4(v.z, f + 8);
#pragma unroll
    for (int i = 0; i < 12; ++i) acc[i] += wgt * f[i];
  }

  if (half == 0) {
#pragma unroll
    for (int c = 0; c < 3; ++c)
      *reinterpret_cast<float4*>(&osum[r][lane * 12 + c * 4]) =
          make_float4(acc[c * 4], acc[c * 4 + 1], acc[c * 4 + 2], acc[c * 4 + 3]);
  }
  __syncthreads();
  if (half == 1) {
#pragma unroll
    for (int i = 0; i < 12; ++i) osum[r][lane * 12 + i] += acc[i];
  }
  __syncthreads();

  // ---- residual add + coalesced store: waves 4-7 store row r ----
  if (half == 1) {
    const float* hrow = hidden + ((size_t)b * L_ + l0 + r) * H_;
    float*       orow = out    + ((size_t)b * L_ + l0 + r) * H_;
#pragma unroll
    for (int c = 0; c < 3; ++c) {
      const int h0 = c * 256 + lane * 4;
      const float4 ov = *reinterpret_cast<const float4*>(&osum[r][h0]);
      const float4 hv = *reinterpret_cast<const float4*>(hrow + h0);
      *reinterpret_cast<float4*>(orow + h0) =
          make_float4(ov.x + hv.x, ov.y + hv.y, ov.z + hv.z, ov.w + hv.w);
    }
  }
}

// ---------------------------------------------------------------------------
extern "C" void kernel_launch(void* const* d_in, const int* in_sizes, int n_in,
                              void* d_out, int out_size, void* d_ws, size_t ws_size,
                              hipStream_t stream) {
  (void)in_sizes; (void)n_in; (void)out_size; (void)ws_size;
  const float* hidden  = (const float*)d_in[0];
  const int*   key_seq = (const int*)d_in[1];
  const int*   vmat    = (const int*)d_in[2];
  const int*   mask    = (const int*)d_in[3];
  const float* key_emb = (const float*)d_in[4];
  const float* val_emb = (const float*)d_in[5];
  float* out = (float*)d_out;

  // ws layout (16B-aligned):
  //   VT8 : VAL_SIZE*H bytes = 7,680,000 B
  //   ET2 : B*H2*K uint      = 1,572,864 B
  unsigned char* VT8 = (unsigned char*)d_ws;
  unsigned*      ET2 = (unsigned*)(VT8 + (size_t)VAL_SIZE_ * H_);

  k_prep<<<TBLK + CBLK, 256, 0, stream>>>(key_seq, key_emb, val_emb, ET2, VT8);
  k_scores_pv<<<SBLK, 512, 0, stream>>>(hidden, ET2, mask, vmat, VT8, out);
}

// Round 9
// 35.060 us; speedup vs baseline: 1.1256x; 1.1256x over previous
//
#include <hip/hip_runtime.h>
#include <math.h>

typedef float    f32x2 __attribute__((ext_vector_type(2)));
typedef float    f32x4 __attribute__((ext_vector_type(4)));
typedef _Float16 f16x2 __attribute__((ext_vector_type(2)));

static constexpr int B_ = 4;
static constexpr int L_ = 256;
static constexpr int K_ = 256;
static constexpr int H_ = 768;
static constexpr int H2_ = H_ / 2;       // 384 f16-pairs per row
static constexpr int VAL_SIZE_ = 10000;
static constexpr float INV_TEMPER = 0.03608439182435161f; // 1/sqrt(768)

// ---------------- f16 pair helpers ----------------
__device__ __forceinline__ unsigned pack_f16x2(float a, float b) {
  f16x2 p = {(_Float16)a, (_Float16)b};   // RNE converts
  return __builtin_bit_cast(unsigned, p);
}
__device__ __forceinline__ float fdot2u(unsigned a, unsigned b, float c) {
#if __has_builtin(__builtin_amdgcn_fdot2)
  return __builtin_amdgcn_fdot2(__builtin_bit_cast(f16x2, a),
                                __builtin_bit_cast(f16x2, b), c, false);
#else
  f16x2 va = __builtin_bit_cast(f16x2, a);
  f16x2 vb = __builtin_bit_cast(f16x2, b);
  return c + (float)va.x * (float)vb.x + (float)va.y * (float)vb.y;
#endif
}

// ---------------- non-temporal load (native vec type) ----------------
__device__ __forceinline__ float4 nt_load4(const float* p) {
  f32x4 v = __builtin_nontemporal_load(reinterpret_cast<const f32x4*>(p));
  return make_float4(v.x, v.y, v.z, v.w);
}

// ---------------- fp8 e4m3fn (OCP) helpers ----------------
#if __has_builtin(__builtin_amdgcn_cvt_pk_fp8_f32)
#define HW_FP8_ENC 1
#endif
#if __has_builtin(__builtin_amdgcn_cvt_pk_f32_fp8)
#define HW_FP8_DEC 1
#endif

__device__ __forceinline__ unsigned fp8_enc1(float f) {
  unsigned s = (__float_as_uint(f) >> 31) << 7;
  float af = fminf(fabsf(f), 448.0f);
  unsigned em;
  if (af < 0.015625f) {
    em = (unsigned)rintf(af * 512.0f);
  } else {
    unsigned m = __float_as_uint(af);
    m += 0x7ffffu + ((m >> 20) & 1u);
    em = (m >> 20) - (120u << 3);
  }
  return s | em;
}
__device__ __forceinline__ float fp8_dec1(unsigned b) {
  unsigned em = b & 0x7fu;
  unsigned sbit = (b & 0x80u) << 24;
  float n = __uint_as_float(sbit | ((em + 960u) << 20));
  float sub = __uint_as_float(sbit | 0x3F800000u) * (float)em * 0.001953125f;
  return em >= 8u ? n : sub;
}
__device__ __forceinline__ unsigned fp8_enc4(float a, float b, float c, float d) {
#ifdef HW_FP8_ENC
  int w = 0;
  w = __builtin_amdgcn_cvt_pk_fp8_f32(a, b, w, false);
  w = __builtin_amdgcn_cvt_pk_fp8_f32(c, d, w, true);
  return (unsigned)w;
#else
  return fp8_enc1(a) | (fp8_enc1(b) << 8) | (fp8_enc1(c) << 16) | (fp8_enc1(d) << 24);
#endif
}
__device__ __forceinline__ void fp8_dec4(unsigned w, float* o) {
#ifdef HW_FP8_DEC
  f32x2 lo = __builtin_amdgcn_cvt_pk_f32_fp8((int)w, false);
  f32x2 hi = __builtin_amdgcn_cvt_pk_f32_fp8((int)w, true);
  o[0] = lo.x; o[1] = lo.y; o[2] = hi.x; o[3] = hi.y;
#else
  o[0] = fp8_dec1(w & 0xffu);
  o[1] = fp8_dec1((w >> 8) & 0xffu);
  o[2] = fp8_dec1((w >> 16) & 0xffu);
  o[3] = fp8_dec1(w >> 24);
#endif
}

static constexpr int TBLK = (K_ / 64) * (H_ / 64) * B_;    // 192 transpose blocks
static constexpr int SBLK = (L_ / 2) * B_;                 // 512 fused blocks
static constexpr int CBLK = (VAL_SIZE_ * H_) / 4096;       // 1875 convert blocks

// ---------------------------------------------------------------------------
// Kernel 1 (prep): blocks [0,TBLK) gather+transpose keys -> f16-pair
// ET2[b][h2][k]; blocks [TBLK, TBLK+CBLK) convert val table f32 -> fp8 VT8.
// block 256.
// ---------------------------------------------------------------------------
__global__ __launch_bounds__(256)
void k_prep(const int* __restrict__ key_seq,
            const float* __restrict__ key_emb,
            const float* __restrict__ vtab,
            unsigned* __restrict__ ET2,
            unsigned char* __restrict__ VT8) {
  __shared__ float tile[64][65];
  const int t = threadIdx.x;

  if (blockIdx.x >= TBLK) {
    const size_t base = (size_t)(blockIdx.x - TBLK) * 4096;
#pragma unroll
    for (int c = 0; c < 4; ++c) {
      const size_t e0 = base + (size_t)c * 1024 + (size_t)t * 4;
      const float4 a = nt_load4(vtab + e0);
      *reinterpret_cast<unsigned*>(VT8 + e0) = fp8_enc4(a.x, a.y, a.z, a.w);
    }
    return;
  }

  const int blk  = blockIdx.x;
  const int kb   = (blk % (K_ / 64)) * 64;
  const int hb   = ((blk / (K_ / 64)) % (H_ / 64)) * 64;
  const int b    = blk / ((K_ / 64) * (H_ / 64));
  const int sub  = t >> 6;
  const int lane = t & 63;

#pragma unroll
  for (int p = 0; p < 16; ++p) {
    const int kl  = p * 4 + sub;
    const int row = key_seq[b * K_ + kb + kl];              // wave-uniform
    tile[kl][lane] = key_emb[(size_t)row * H_ + hb + lane]; // coalesced
  }
  __syncthreads();
#pragma unroll
  for (int p = 0; p < 8; ++p) {
    const int hl2 = p * 4 + sub;                            // 0..31
    ET2[((size_t)b * H2_ + (hb >> 1) + hl2) * K_ + kb + lane] =
        pack_f16x2(tile[lane][2 * hl2], tile[lane][2 * hl2 + 1]);
  }
}

// ---------------------------------------------------------------------------
// Kernel 2 (fused, 2 l-rows/block): scores + masked softmax + compaction +
// PV + residual. 512 blocks x 512 threads -> 2 blocks/CU, 16 waves/CU.
// Scores: all 8 waves, h-split 8x48, ET2 slice shared by both rows.
// PV: wave w -> row r=w&1, quarter q=w>>1; full 768B fp8 row per wave per j,
// j stride 4; 2-step LDS tree combine. No global P.
// ---------------------------------------------------------------------------
__global__ __launch_bounds__(512)
void k_scores_pv(const float* __restrict__ hidden,
                 const unsigned* __restrict__ ET2,
                 const int* __restrict__ mask,
                 const int* __restrict__ vmat,
                 const unsigned char* __restrict__ VT8,
                 float* __restrict__ out) {
  __shared__ unsigned hid2[2 * H2_];    // 3 KB  (f16 pairs along h)
  __shared__ float4   part[2][512];     // 16 KB
  __shared__ int      vmat_lds[2][K_];  // 2 KB
  __shared__ float    pw[2][K_];        // 2 KB  compacted weights
  __shared__ int      vidx[2][K_];      // 2 KB  compacted indices
  __shared__ float    osum[2][2][H_];   // 12 KB row partials (2-way tree)
  __shared__ int      nrow[2];

  const int t  = threadIdx.x;
  const int l0 = (blockIdx.x & 127) * 2;   // 128 l-groups per batch
  const int b  = blockIdx.x >> 7;

  // ---- stage: 2 hidden rows as f16 pairs; 2 vmat rows ----
  const float* hsrc = hidden + ((size_t)b * L_ + l0) * H_;
  for (int i = t; i < 2 * H2_; i += 512) {
    const float2 hv = *reinterpret_cast<const float2*>(hsrc + 2 * i);
    hid2[i] = pack_f16x2(hv.x, hv.y);
  }
  if (t >= 256 && t < 384) {
    const int i  = t - 256;               // 0..127
    const int r  = i >> 6;
    const int c4 = (i & 63) * 4;
    *reinterpret_cast<int4*>(&vmat_lds[r][c4]) =
        *reinterpret_cast<const int4*>(vmat + ((size_t)b * L_ + l0 + r) * K_ + c4);
  }
  __syncthreads();

  // ---- scores: all 8 waves, 48 h2 each ----
  {
    const int kq = t & 63;
    const int hq = t >> 6;                // 0..7
    float4 acc[2];
#pragma unroll
    for (int l = 0; l < 2; ++l) acc[l] = make_float4(0.f, 0.f, 0.f, 0.f);

    const unsigned* etp =
        ET2 + (size_t)b * H2_ * K_ + (size_t)(hq * 48) * K_ + kq * 4;
    const int hbase2 = hq * 48;
#pragma unroll 4
    for (int hh = 0; hh < 48; ++hh) {
      const uint4 e = *reinterpret_cast<const uint4*>(etp + (size_t)hh * K_);
#pragma unroll
      for (int l = 0; l < 2; ++l) {
        const unsigned hv2 = hid2[l * H2_ + hbase2 + hh];  // LDS broadcast
        acc[l].x = fdot2u(e.x, hv2, acc[l].x);
        acc[l].y = fdot2u(e.y, hv2, acc[l].y);
        acc[l].z = fdot2u(e.z, hv2, acc[l].z);
        acc[l].w = fdot2u(e.w, hv2, acc[l].w);
      }
    }
#pragma unroll
    for (int l = 0; l < 2; ++l) part[l][t] = acc[l];
  }
  __syncthreads();

  // ---- softmax + compaction: waves 0,1 (one per row) ----
  if (t < 128) {
    const int kq2 = t & 63;
    const int l2  = t >> 6;
    float4 a = part[l2][kq2];
#pragma unroll
    for (int c = 1; c < 8; ++c) {
      const float4 pc = part[l2][c * 64 + kq2];
      a.x += pc.x; a.y += pc.y; a.z += pc.z; a.w += pc.w;
    }

    const int lrow = l0 + l2;
    const int4 m4 = *reinterpret_cast<const int4*>(
        mask + ((size_t)b * L_ + lrow) * K_ + kq2 * 4);
    float ex[4];
    ex[0] = (m4.x > 0) ? expf(a.x * INV_TEMPER) : 0.f;
    ex[1] = (m4.y > 0) ? expf(a.y * INV_TEMPER) : 0.f;
    ex[2] = (m4.z > 0) ? expf(a.z * INV_TEMPER) : 0.f;
    ex[3] = (m4.w > 0) ? expf(a.w * INV_TEMPER) : 0.f;

    float s = ex[0] + ex[1] + ex[2] + ex[3];
#pragma unroll
    for (int off = 32; off > 0; off >>= 1) s += __shfl_down(s, off);
    const float tot = __shfl(s, 0) + 1e-10f;
    const float rtot = 1.0f / tot;

    const unsigned long long lt = (1ull << kq2) - 1ull;
    unsigned long long m[4];
    int run = 0;
    int pos[4];
#pragma unroll
    for (int cc = 0; cc < 4; ++cc) {
      m[cc] = __ballot(ex[cc] != 0.f);
      pos[cc] = run + (int)__popcll(m[cc] & lt);
      run += (int)__popcll(m[cc]);
    }
#pragma unroll
    for (int cc = 0; cc < 4; ++cc) {
      if (ex[cc] != 0.f) {
        pw[l2][pos[cc]]   = ex[cc] * rtot;
        vidx[l2][pos[cc]] = vmat_lds[l2][kq2 * 4 + cc];
      }
    }
    if (kq2 == 0) nrow[l2] = run;
  }
  __syncthreads();

  // ---- PV: wave w -> row r=w&1, quarter q=w>>1 ----
  const int w    = t >> 6;
  const int lane = t & 63;
  const int r    = w & 1;
  const int q    = w >> 1;       // 0..3
  const int n    = nrow[r];

  float acc[12];
#pragma unroll
  for (int i = 0; i < 12; ++i) acc[i] = 0.f;

#pragma unroll 4
  for (int j = q; j < n; j += 4) {
    const float wgt = pw[r][j];                   // LDS broadcast
    const int   idx = vidx[r][j];
    const uint3 v = *reinterpret_cast<const uint3*>(
        VT8 + (size_t)idx * H_ + lane * 12);      // 12B x 64 lanes = 768B row
    float f[12];
    fp8_dec4(v.x, f);
    fp8_dec4(v.y, f + 4);
    fp8_dec4(v.z, f + 8);
#pragma unroll
    for (int i = 0; i < 12; ++i) acc[i] += wgt * f[i];
  }

  // 2-step tree combine: q0,q1 write; q2,q3 add; then q0 stores.
  if (q < 2) {
#pragma unroll
    for (int c = 0; c < 3; ++c)
      *reinterpret_cast<float4*>(&osum[r][q][lane * 12 + c * 4]) =
          make_float4(acc[c * 4], acc[c * 4 + 1], acc[c * 4 + 2], acc[c * 4 + 3]);
  }
  __syncthreads();
  if (q >= 2) {
#pragma unroll
    for (int i = 0; i < 12; ++i) osum[r][q - 2][lane * 12 + i] += acc[i];
  }
  __syncthreads();

  // ---- residual add + coalesced store: wave q==0 stores row r ----
  if (q == 0) {
    const float* hrow = hidden + ((size_t)b * L_ + l0 + r) * H_;
    float*       orow = out    + ((size_t)b * L_ + l0 + r) * H_;
#pragma unroll
    for (int c = 0; c < 3; ++c) {
      const int h0 = c * 256 + lane * 4;
      const float4 o0 = *reinterpret_cast<const float4*>(&osum[r][0][h0]);
      const float4 o1 = *reinterpret_cast<const float4*>(&osum[r][1][h0]);
      const float4 hv = *reinterpret_cast<const float4*>(hrow + h0);
      *reinterpret_cast<float4*>(orow + h0) =
          make_float4(o0.x + o1.x + hv.x, o0.y + o1.y + hv.y,
                      o0.z + o1.z + hv.z, o0.w + o1.w + hv.w);
    }
  }
}

// ---------------------------------------------------------------------------
extern "C" void kernel_launch(void* const* d_in, const int* in_sizes, int n_in,
                              void* d_out, int out_size, void* d_ws, size_t ws_size,
                              hipStream_t stream) {
  (void)in_sizes; (void)n_in; (void)out_size; (void)ws_size;
  const float* hidden  = (const float*)d_in[0];
  const int*   key_seq = (const int*)d_in[1];
  const int*   vmat    = (const int*)d_in[2];
  const int*   mask    = (const int*)d_in[3];
  const float* key_emb = (const float*)d_in[4];
  const float* val_emb = (const float*)d_in[5];
  float* out = (float*)d_out;

  // ws layout (16B-aligned):
  //   VT8 : VAL_SIZE*H bytes = 7,680,000 B
  //   ET2 : B*H2*K uint      = 1,572,864 B
  unsigned char* VT8 = (unsigned char*)d_ws;
  unsigned*      ET2 = (unsigned*)(VT8 + (size_t)VAL_SIZE_ * H_);

  k_prep<<<TBLK + CBLK, 256, 0, stream>>>(key_seq, key_emb, val_emb, ET2, VT8);
  k_scores_pv<<<SBLK, 512, 0, stream>>>(hidden, ET2, mask, vmat, VT8, out);
}